// Round 1
// baseline (460.481 us; speedup 1.0000x reference)
//
#include <hip/hip_runtime.h>

#define NSHOTS 4
#define NT     512
#define NZ     256
#define NX     256
#define NRECS  128

static constexpr float DTf    = 0.001f;
static constexpr float INVDH2 = 1.0f / (10.0f * 10.0f);

#define KSTEPS 16                 // fused steps per phase
#define TILEX  32                 // interior half-tile width  (x)
#define TILEZ  16                 // interior half-tile height (z)
#define RPT    6                  // ext rows per thread: EXTZ(48)/NWAVES(8)
#define NPAIRS 3                  // RPT/2
#define NWAVES 8
#define BLOCK  512
#define NTZ    16                 // z-tiles per shot
#define NTX    8                  // x-tiles per shot
#define NTILES (NSHOTS * NTZ * NTX)   // 512 half-tiles; each WG owns 2 (shot s and s+2)
#define NWG    256                // one WG per CU (co-resident)
#define NPHASE (NT / KSTEPS)      // 32
#define LSTRIDE 32                // dwords between flags (128 B)
#define SHOT2OFF (2 * NZ * NX)    // field offset from tile A to tile B (same z/x)

typedef float v2f __attribute__((ext_vector_type(2)));

// lane i <- lane i-1 (left x-neighbor); OOB lane 0 reads 0 (bound_ctrl=1)
__device__ __forceinline__ float nbr_left(float v) {
  return __int_as_float(__builtin_amdgcn_update_dpp(
      0, __float_as_int(v), 0x138 /*WAVE_SHR1*/, 0xf, 0xf, true));
}
// lane i <- lane i+1 (right x-neighbor); OOB lane 63 reads 0
__device__ __forceinline__ float nbr_right(float v) {
  return __int_as_float(__builtin_amdgcn_update_dpp(
      0, __float_as_int(v), 0x130 /*WAVE_SHL1*/, 0xf, 0xf, true));
}

// LLC-coherent (cross-XCD) access: agent-scope relaxed -> sc0 sc1.
__device__ __forceinline__ float gload(const float* p) {
  return __hip_atomic_load(p, __ATOMIC_RELAXED, __HIP_MEMORY_SCOPE_AGENT);
}
__device__ __forceinline__ void gstore(float* p, float v) {
  __hip_atomic_store(p, v, __ATOMIC_RELAXED, __HIP_MEMORY_SCOPE_AGENT);
}
__device__ __forceinline__ unsigned fload(const unsigned* p) {
  return __hip_atomic_load(p, __ATOMIC_RELAXED, __HIP_MEMORY_SCOPE_AGENT);
}
__device__ __forceinline__ void fstore(unsigned* p, unsigned v) {
  __hip_atomic_store(p, v, __ATOMIC_RELAXED, __HIP_MEMORY_SCOPE_AGENT);
}

__global__ __launch_bounds__(BLOCK, 2) void wave_pk(
    float* __restrict__ f0c, float* __restrict__ f0p,   // pair 0 (even-phase writes)
    float* __restrict__ f1c, float* __restrict__ f1p,   // pair 1 (odd-phase writes)
    const float* __restrict__ vp, const float* __restrict__ xwav,
    const int* __restrict__ src_z, const int* __restrict__ src_x,
    const int* __restrict__ rec_z, const int* __restrict__ rec_x,
    float* __restrict__ out,                            // [NSHOTS*NT*NRECS]
    unsigned* __restrict__ bar)                         // wFlag[NTILES], rFlag[NTILES] @128B
{
  const int bid  = blockIdx.x;
  const int sA   = bid >> 7;           // shots 0..1
  const int sB   = sA + 2;             // shots 2..3 (same tz/tx geometry)
  const int tz   = (bid >> 3) & 15;
  const int tx   = bid & 7;
  const int tid  = threadIdx.x;
  const int w    = tid >> 6;
  const int lane = tid & 63;

  const int gz0 = tz * TILEZ - KSTEPS;
  const int gx0 = tx * TILEX - KSTEPS;
  const int gx  = gx0 + lane;
  const int zb  = w * RPT;
  const int ilx = lane - KSTEPS;
  const bool xin = (unsigned)ilx < (unsigned)TILEX;

  __shared__ float haloTop[2][NWAVES][64];
  __shared__ float haloBot[2][NWAVES][64];
  __shared__ float recTile[2][TILEZ][TILEX + 1];
  __shared__ int   cntS;
  __shared__ int   lzS[NRECS], lxS[NRECS];
  __shared__ unsigned pkS[NRECS];

  // writeback rows: interior z-row && interior lane (per-row mask, rows split waves)
  unsigned wbMask = 0;
  if (xin) {
    #pragma unroll
    for (int i = 0; i < RPT; ++i)
      if ((unsigned)(zb + i - KSTEPS) < (unsigned)TILEZ) wbMask |= 1u << i;
  }

  // ---- prologue: receiver compaction + masks, once per tile ----
  int nRecA = 0, nRecB = 0;
  int myRA = 0, myLzA = 0, myLxA = 0;
  int myRB = 0, myLzB = 0, myLxB = 0;
  unsigned recMaskA = 0, recMaskB = 0;
  #pragma unroll
  for (int tt = 0; tt < 2; ++tt) {
    const int s = tt ? sB : sA;
    if (tid == 0) cntS = 0;
    __syncthreads();
    if (tid < NRECS) {
      const int lz = rec_z[s * NRECS + tid] - tz * TILEZ;
      const int lx = rec_x[s * NRECS + tid] - tx * TILEX;
      lzS[tid] = lz; lxS[tid] = lx;
      if ((unsigned)lz < (unsigned)TILEZ && (unsigned)lx < (unsigned)TILEX) {
        const int k = atomicAdd(&cntS, 1);
        pkS[k] = (unsigned)tid | ((unsigned)lz << 8) | ((unsigned)lx << 16);
      }
    }
    __syncthreads();
    const int n = cntS;
    int mR = 0, mLz = 0, mLx = 0;
    if (tid < n) {
      const unsigned p = pkS[tid];
      mR = p & 255; mLz = (p >> 8) & 31; mLx = (p >> 16) & 31;
    }
    unsigned rm = 0;
    if (xin) {
      for (int r = 0; r < NRECS; ++r)
        if (lxS[r] == ilx && (unsigned)lzS[r] < (unsigned)TILEZ) {
          const int i = lzS[r] - (zb - KSTEPS);
          if ((unsigned)i < (unsigned)RPT) rm |= 1u << i;
        }
    }
    __syncthreads();                       // done with lzS/lxS/pkS/cntS
    if (tt == 0) { nRecA = n; myRA = mR; myLzA = mLz; myLxA = mLx; recMaskA = rm; }
    else         { nRecB = n; myRB = mR; myLzB = mLz; myLxB = mLx; recMaskB = rm; }
  }

  // neighbor flag indices for the 8 surrounding tiles (tid<8)
  int nbA = -1;
  if (tid < 8) {
    const int k  = (tid < 4) ? tid : tid + 1;   // skip center of 3x3
    const int dz = k / 3 - 1, dx = k % 3 - 1;
    const int qz = tz + dz, qx = tx + dx;
    if ((unsigned)qz < (unsigned)NTZ && (unsigned)qx < (unsigned)NTX)
      nbA = (sA << 7) | (qz << 3) | qx;
  }
  const int nbB  = (nbA >= 0) ? nbA + 256 : -1;
  const int idxA = (sA << 7) | (tz << 3) | tx;
  const int idxB = idxA + 256;
  unsigned* wFlg = bar;
  unsigned* rFlg = bar + (size_t)NTILES * LSTRIDE;

  auto pollGE = [&](unsigned* base, int nb, unsigned target) {
    if (nb >= 0) {
      const unsigned* p = base + (size_t)nb * LSTRIDE;
      while (fload(p) < target) __builtin_amdgcn_s_sleep(1);
    }
  };

  // source masks, packed per row-pair, per tile
  v2f srcM2A[NPAIRS], srcM2B[NPAIRS];
  #pragma unroll
  for (int tt = 0; tt < 2; ++tt) {
    const int s   = tt ? sB : sA;
    const int slz = src_z[s] - gz0;
    const int slx = src_x[s] - gx0;
    const bool mine = (slx == lane) && ((unsigned)(slz - zb) < (unsigned)RPT);
    const int si = slz - zb;
    #pragma unroll
    for (int p = 0; p < NPAIRS; ++p) {
      v2f m;
      m.x = (mine && si == 2 * p)     ? 1.0f : 0.0f;
      m.y = (mine && si == 2 * p + 1) ? 1.0f : 0.0f;
      if (tt == 0) srcM2A[p] = m; else srcM2B[p] = m;
    }
  }

  // per-row addresses/validity; c2 and d2=2-4c2 (vp is shot-independent: shared A/B)
  const bool xok = (unsigned)gx < (unsigned)NX;
  int   offRow[RPT];
  bool  okRow[RPT];
  v2f c22[NPAIRS], d22[NPAIRS];
  v2f a2A[NPAIRS], b2A[NPAIRS], a2B[NPAIRS], b2B[NPAIRS];
  #pragma unroll
  for (int p = 0; p < NPAIRS; ++p) {
    #pragma unroll
    for (int h = 0; h < 2; ++h) {
      const int i  = 2 * p + h;
      const int gz = gz0 + zb + i;
      const bool ok = xok && ((unsigned)gz < (unsigned)NZ);
      okRow[i]  = ok;
      offRow[i] = ok ? ((sA * NZ + gz) * NX + gx) : 0;
      float v = ok ? vp[gz * NX + gx] : 0.0f;
      v *= DTf;
      const float c2 = v * v * INVDH2;
      if (h == 0) { c22[p].x = c2; d22[p].x = 2.0f - 4.0f * c2; }
      else        { c22[p].y = c2; d22[p].y = 2.0f - 4.0f * c2; }
    }
    a2A[p] = (v2f)(0.0f); b2A[p] = (v2f)(0.0f);
    a2B[p] = (v2f)(0.0f); b2B[p] = (v2f)(0.0f);
  }

  float amp[KSTEPS], recv[KSTEPS];

  auto load_amp = [&](int s, int t0) {
    const float4* xw4 = (const float4*)(xwav + s * NT + t0);
    #pragma unroll
    for (int q = 0; q < KSTEPS / 4; ++q) {
      const float4 v = xw4[q];
      amp[4 * q + 0] = (v.x * DTf) * DTf;
      amp[4 * q + 1] = (v.y * DTf) * DTf;
      amp[4 * q + 2] = (v.z * DTf) * DTf;
      amp[4 * q + 3] = (v.w * DTf) * DTf;
    }
  };

  // one step, row-pair packed: p' = d2*c + c2*sum - prev (+ src)
  auto do_step = [&](v2f (&cur)[NPAIRS], v2f (&nxt)[NPAIRS],
                     const v2f (&sm)[NPAIRS], int tau,
                     unsigned rMask, int nR, int mLz, int mLx) {
    const int pb = tau & 1;
    haloTop[pb][w][lane] = cur[0].x;
    haloBot[pb][w][lane] = cur[NPAIRS - 1].y;
    __syncthreads();
    if (tau > 0 && tid < nR) recv[tau - 1] = recTile[1 - pb][mLz][mLx];
    const float up0 = (w > 0)          ? haloBot[pb][w - 1][lane] : 0.0f;
    const float dn  = (w < NWAVES - 1) ? haloTop[pb][w + 1][lane] : 0.0f;
    const v2f av = { amp[tau], amp[tau] };
    #pragma unroll
    for (int p = 0; p < NPAIRS; ++p) {
      const float cx = cur[p].x, cy = cur[p].y;
      const float upx = (p == 0)          ? up0 : cur[p - 1].y;
      const float dny = (p == NPAIRS - 1) ? dn  : cur[p + 1].x;
      v2f ud, lr;
      ud.x = upx + cy;
      ud.y = cx + dny;
      lr.x = nbr_left(cx) + nbr_right(cx);
      lr.y = nbr_left(cy) + nbr_right(cy);
      const v2f sum = ud + lr;
      v2f t = __builtin_elementwise_fma(c22[p], sum, -nxt[p]);
      t = __builtin_elementwise_fma(d22[p], cur[p], t);
      t = __builtin_elementwise_fma(sm[p], av, t);
      nxt[p] = t;
    }
    if (rMask) {
      #pragma unroll
      for (int i = 0; i < RPT; ++i)
        if (rMask & (1u << i))
          recTile[pb][zb + i - KSTEPS][ilx] = (i & 1) ? nxt[i >> 1].y : nxt[i >> 1].x;
    }
  };

  // ===== pipelined main loop: C_A(ph) | W_A+R_B | C_B(ph) | W_B+R_A(ph+1) =====
  #pragma unroll 1
  for (int ph = 0; ph < NPHASE; ++ph) {
    const int t0 = ph * KSTEPS;

    // ---------------- tile A: 16 steps ----------------
    load_amp(sA, t0);
    #pragma unroll
    for (int hh = 0; hh < KSTEPS / 2; ++hh) {
      do_step(a2A, b2A, srcM2A, 2 * hh,     recMaskA, nRecA, myLzA, myLxA);
      do_step(b2A, a2A, srcM2A, 2 * hh + 1, recMaskA, nRecA, myLzA, myLxA);
    }

    // ------ boundary A(ph): W_A(ph) + R_B(ph); flags were set ~half a phase ago ------
    if (ph >= 2 && ph < NPHASE - 1) pollGE(rFlg, nbA, (unsigned)(ph - 1)); // overwrite ok
    if (ph >= 1)                    pollGE(wFlg, nbB, (unsigned)ph);       // B data ready
    __syncthreads();                 // recTile[1] ready WG-wide + polls done
    if (tid < nRecA) {
      recv[KSTEPS - 1] = recTile[1][myLzA][myLxA];
      #pragma unroll
      for (int t = 0; t < KSTEPS; ++t)
        out[(sA * NT + (t0 + t)) * NRECS + myRA] = recv[t];
    }
    if (ph < NPHASE - 1 && wbMask) {           // A interior writeback, pair ph&1
      float* wc = (ph & 1) ? f1c : f0c;
      float* wp = (ph & 1) ? f1p : f0p;
      #pragma unroll
      for (int i = 0; i < RPT; ++i)
        if (wbMask & (1u << i)) {
          gstore(wc + offRow[i], (i & 1) ? a2A[i >> 1].y : a2A[i >> 1].x);
          gstore(wp + offRow[i], (i & 1) ? b2A[i >> 1].y : b2A[i >> 1].x);
        }
    }
    if (ph >= 1) {                             // B ring reload, pair (ph-1)&1
      const float* rc = (ph & 1) ? f0c : f1c;
      const float* rp = (ph & 1) ? f0p : f1p;
      #pragma unroll
      for (int i = 0; i < RPT; ++i)
        if (!(wbMask & (1u << i))) {
          const float cv = okRow[i] ? gload(rc + offRow[i] + SHOT2OFF) : 0.0f;
          const float pv = okRow[i] ? gload(rp + offRow[i] + SHOT2OFF) : 0.0f;
          if (i & 1) { a2B[i >> 1].y = cv; b2B[i >> 1].y = pv; }
          else       { a2B[i >> 1].x = cv; b2B[i >> 1].x = pv; }
        }
    }
    load_amp(sB, t0);
    __builtin_amdgcn_s_waitcnt(0);   // A stores ack'd + B reload complete (per wave)
    __syncthreads();                 // whole WG drained
    if (tid == 0) {
      if (ph < NPHASE - 1) fstore(wFlg + (size_t)idxA * LSTRIDE, (unsigned)(ph + 1));
      if (ph >= 1)         fstore(rFlg + (size_t)idxB * LSTRIDE, (unsigned)ph);
    }

    // ---------------- tile B: 16 steps ----------------
    #pragma unroll
    for (int hh = 0; hh < KSTEPS / 2; ++hh) {
      do_step(a2B, b2B, srcM2B, 2 * hh,     recMaskB, nRecB, myLzB, myLxB);
      do_step(b2B, a2B, srcM2B, 2 * hh + 1, recMaskB, nRecB, myLzB, myLxB);
    }

    // ------ boundary B(ph): W_B(ph) + R_A(ph+1) ------
    if (ph >= 2 && ph < NPHASE - 1) pollGE(rFlg, nbB, (unsigned)(ph - 1));
    if (ph < NPHASE - 1)            pollGE(wFlg, nbA, (unsigned)(ph + 1));
    __syncthreads();
    if (tid < nRecB) {
      recv[KSTEPS - 1] = recTile[1][myLzB][myLxB];
      #pragma unroll
      for (int t = 0; t < KSTEPS; ++t)
        out[(sB * NT + (t0 + t)) * NRECS + myRB] = recv[t];
    }
    if (ph < NPHASE - 1) {
      float* wc = (ph & 1) ? f1c : f0c;        // B writeback, pair ph&1
      float* wp = (ph & 1) ? f1p : f0p;
      if (wbMask) {
        #pragma unroll
        for (int i = 0; i < RPT; ++i)
          if (wbMask & (1u << i)) {
            gstore(wc + offRow[i] + SHOT2OFF, (i & 1) ? a2B[i >> 1].y : a2B[i >> 1].x);
            gstore(wp + offRow[i] + SHOT2OFF, (i & 1) ? b2B[i >> 1].y : b2B[i >> 1].x);
          }
      }
      const float* rc = (ph & 1) ? f1c : f0c;  // A ring reload for ph+1, pair ph&1
      const float* rp = (ph & 1) ? f1p : f0p;
      #pragma unroll
      for (int i = 0; i < RPT; ++i)
        if (!(wbMask & (1u << i))) {
          const float cv = okRow[i] ? gload(rc + offRow[i]) : 0.0f;
          const float pv = okRow[i] ? gload(rp + offRow[i]) : 0.0f;
          if (i & 1) { a2A[i >> 1].y = cv; b2A[i >> 1].y = pv; }
          else       { a2A[i >> 1].x = cv; b2A[i >> 1].x = pv; }
        }
      __builtin_amdgcn_s_waitcnt(0);
      __syncthreads();
      if (tid == 0) {
        fstore(wFlg + (size_t)idxB * LSTRIDE, (unsigned)(ph + 1));
        fstore(rFlg + (size_t)idxA * LSTRIDE, (unsigned)(ph + 1));
      }
    }
  }
}

extern "C" void kernel_launch(void* const* d_in, const int* in_sizes, int n_in,
                              void* d_out, int out_size, void* d_ws, size_t ws_size,
                              hipStream_t stream) {
  const float* x     = (const float*)d_in[0];
  const float* vp    = (const float*)d_in[1];
  const int*   src_z = (const int*)d_in[2];
  const int*   src_x = (const int*)d_in[3];
  const int*   rec_z = (const int*)d_in[4];
  const int*   rec_x = (const int*)d_in[5];
  float* out = (float*)d_out;

  float* ws = (float*)d_ws;
  const size_t F = (size_t)NSHOTS * NZ * NX;
  float* f0c = ws;
  float* f0p = ws + F;
  float* f1c = ws + 2 * F;
  float* f1p = ws + 3 * F;
  unsigned* bar = (unsigned*)(ws + 4 * F);

  // zero the p2p flags (wFlag + rFlag for 512 half-tiles, 128B-strided)
  hipMemsetAsync(bar, 0, 2 * (size_t)NTILES * LSTRIDE * sizeof(unsigned), stream);

  wave_pk<<<dim3(NWG), dim3(BLOCK), 0, stream>>>(
      f0c, f0p, f1c, f1p, vp, x, src_z, src_x, rec_z, rec_x, out, bar);
}

// Round 2
// 317.586 us; speedup vs baseline: 1.4499x; 1.4499x over previous
//
#include <hip/hip_runtime.h>

#define NSHOTS 4
#define NT     512
#define NZ     256
#define NX     256
#define NRECS  128

static constexpr float DTf    = 0.001f;
static constexpr float INVDH2 = 1.0f / (10.0f * 10.0f);

#define KSTEPS 16                 // fused steps per phase
#define TILE   32                 // interior tile edge
#define RPT    8                  // ext rows per thread (4 float2 pairs)
#define NPAIRS 4                  // RPT/2
#define NWAVES 8
#define BLOCK  512
#define NWG    (NSHOTS * 64)      // 256 WGs, one per CU (co-resident)
#define NPHASE (NT / KSTEPS)      // 32
#define LSTRIDE 32                // dwords between flags (128 B)

typedef float v2f __attribute__((ext_vector_type(2)));

// lane i <- lane i-1 (left x-neighbor); OOB lane 0 reads 0 (bound_ctrl=1,
// matches zero pad; correctness verified R9)
__device__ __forceinline__ float nbr_left(float v) {
  return __int_as_float(__builtin_amdgcn_update_dpp(
      0, __float_as_int(v), 0x138 /*WAVE_SHR1*/, 0xf, 0xf, true));
}
// lane i <- lane i+1 (right x-neighbor); OOB lane 63 reads 0
__device__ __forceinline__ float nbr_right(float v) {
  return __int_as_float(__builtin_amdgcn_update_dpp(
      0, __float_as_int(v), 0x130 /*WAVE_SHL1*/, 0xf, 0xf, true));
}

// LLC-coherent (cross-XCD) access: agent-scope relaxed -> sc0 sc1.
__device__ __forceinline__ float gload(const float* p) {
  return __hip_atomic_load(p, __ATOMIC_RELAXED, __HIP_MEMORY_SCOPE_AGENT);
}
__device__ __forceinline__ void gstore(float* p, float v) {
  __hip_atomic_store(p, v, __ATOMIC_RELAXED, __HIP_MEMORY_SCOPE_AGENT);
}
__device__ __forceinline__ unsigned fload(const unsigned* p) {
  return __hip_atomic_load(p, __ATOMIC_RELAXED, __HIP_MEMORY_SCOPE_AGENT);
}
__device__ __forceinline__ void fstore(unsigned* p, unsigned v) {
  __hip_atomic_store(p, v, __ATOMIC_RELAXED, __HIP_MEMORY_SCOPE_AGENT);
}

__global__ __launch_bounds__(BLOCK, 4) void wave_pk(
    float* __restrict__ f0c, float* __restrict__ f0p,   // pair 0 (even-phase writes)
    float* __restrict__ f1c, float* __restrict__ f1p,   // pair 1 (odd-phase writes)
    const float* __restrict__ vp, const float* __restrict__ xwav,
    const int* __restrict__ src_z, const int* __restrict__ src_x,
    const int* __restrict__ rec_z, const int* __restrict__ rec_x,
    float* __restrict__ out,                            // [NSHOTS*NT*NRECS]
    unsigned* __restrict__ bar)                         // wFlag[NWG] @128B
{
  const int bid  = blockIdx.x;
  const int s    = bid >> 6;
  const int tz   = (bid >> 3) & 7;
  const int tx   = bid & 7;
  const int tid  = threadIdx.x;
  const int w    = tid >> 6;
  const int lane = tid & 63;

  const int gz0 = tz * TILE - KSTEPS;
  const int gx0 = tx * TILE - KSTEPS;
  const int gx  = gx0 + lane;
  const int zb  = w * RPT;

  __shared__ float haloTop[2][NWAVES][64];
  __shared__ float haloBot[2][NWAVES][64];
  __shared__ float recTile[2][TILE][TILE + 1];
  __shared__ int   cntS;
  __shared__ int   lzA[NRECS], lxA[NRECS];
  __shared__ unsigned pkA[NRECS];

  // ---- prologue: receiver compaction + masks (as R0) ----
  if (tid == 0) cntS = 0;
  __syncthreads();
  if (tid < NRECS) {
    const int lz = rec_z[s * NRECS + tid] - tz * TILE;
    const int lx = rec_x[s * NRECS + tid] - tx * TILE;
    lzA[tid] = lz; lxA[tid] = lx;
    if ((unsigned)lz < (unsigned)TILE && (unsigned)lx < (unsigned)TILE) {
      const int k = atomicAdd(&cntS, 1);
      pkA[k] = (unsigned)tid | ((unsigned)lz << 8) | ((unsigned)lx << 16);
    }
  }
  __syncthreads();
  const int nRec = cntS;
  int myR = 0, myLz = 0, myLx = 0;
  if (tid < nRec) {
    const unsigned p = pkA[tid];
    myR = p & 255; myLz = (p >> 8) & 31; myLx = (p >> 16) & 31;
  }
  const bool wbRow = (w >= 2 && w < 6) && (lane >= KSTEPS && lane < KSTEPS + TILE);
  const int  ilz   = (w - 2) * RPT;
  const int  ilx   = lane - KSTEPS;
  unsigned recMask = 0;
  if (wbRow) {
    for (int r = 0; r < NRECS; ++r)
      if (lxA[r] == ilx && (unsigned)(lzA[r] - ilz) < (unsigned)RPT)
        recMask |= 1u << (lzA[r] - ilz);
  }

  // neighbor bid for flag lanes (tid<8 -> the 8 surrounding tiles, same shot)
  int nb = -1;
  if (tid < 8) {
    const int k  = (tid < 4) ? tid : tid + 1;   // skip center of 3x3
    const int dz = k / 3 - 1, dx = k % 3 - 1;
    const int qz = tz + dz, qx = tx + dx;
    if ((unsigned)qz < 8u && (unsigned)qx < 8u)
      nb = (s << 6) | (qz << 3) | qx;
  }
  unsigned* wF = bar;

  auto pollGE = [&](unsigned* base, unsigned target) {
    if (nb >= 0) {
      while (fload(base + (size_t)nb * LSTRIDE) < target)
        __builtin_amdgcn_s_sleep(1);
    }
  };

  // source mask, packed per row-pair
  const int slz = src_z[s] - gz0;
  const int slx = src_x[s] - gx0;
  const bool srcMine = (slx == lane) && ((unsigned)(slz - zb) < (unsigned)RPT);
  const int  srcI = slz - zb;
  v2f srcM2[NPAIRS];
  #pragma unroll
  for (int p = 0; p < NPAIRS; ++p) {
    srcM2[p].x = (srcMine && srcI == 2 * p)     ? 1.0f : 0.0f;
    srcM2[p].y = (srcMine && srcI == 2 * p + 1) ? 1.0f : 0.0f;
  }

  // phase-invariant per-row addresses/validity; c2 and d2=2-4c2 packed
  const bool xok = (unsigned)gx < (unsigned)NX;
  int   offRow[RPT];
  bool  okRow[RPT];
  v2f a2[NPAIRS], b2[NPAIRS], c22[NPAIRS], d22[NPAIRS];
  #pragma unroll
  for (int p = 0; p < NPAIRS; ++p) {
    #pragma unroll
    for (int h = 0; h < 2; ++h) {
      const int i  = 2 * p + h;
      const int gz = gz0 + zb + i;
      const bool ok = xok && ((unsigned)gz < (unsigned)NZ);
      okRow[i]  = ok;
      offRow[i] = ok ? ((s * NZ + gz) * NX + gx) : 0;
      float v = ok ? vp[gz * NX + gx] : 0.0f;
      v *= DTf;
      const float c2 = v * v * INVDH2;
      if (h == 0) { c22[p].x = c2; d22[p].x = 2.0f - 4.0f * c2; }
      else        { c22[p].y = c2; d22[p].y = 2.0f - 4.0f * c2; }
    }
    a2[p] = (v2f)(0.0f); b2[p] = (v2f)(0.0f);
  }

  #pragma unroll 1
  for (int ph = 0; ph < NPHASE; ++ph) {
    const int t0 = ph * KSTEPS;

    // 16 source amps via 4 vector loads (independent of flags -> before poll)
    float amp[KSTEPS];
    {
      const float4* xw4 = (const float4*)(xwav + s * NT + t0);
      #pragma unroll
      for (int q = 0; q < KSTEPS / 4; ++q) {
        const float4 v = xw4[q];
        amp[4 * q + 0] = (v.x * DTf) * DTf;
        amp[4 * q + 1] = (v.y * DTf) * DTf;
        amp[4 * q + 2] = (v.z * DTf) * DTf;
        amp[4 * q + 3] = (v.w * DTf) * DTf;
      }
    }

    if (ph > 0) {
      // single handshake: wF_nb >= ph certifies neighbors finished ALL of
      // phase ph-1 (writeback drained AND their reload of pair ph&1 done),
      // so it covers both the data dep (my reload below) and the anti-dep
      // (my writeback to pair ph&1 at the end of this phase).
      pollGE(wF, (unsigned)ph);
      __syncthreads();
      const float* rc = (ph & 1) ? f0c : f1c;
      const float* rp = (ph & 1) ? f0p : f1p;
      if (!wbRow) {                    // interior threads keep a,b in regs
        #pragma unroll
        for (int p = 0; p < NPAIRS; ++p) {
          a2[p].x = okRow[2 * p]     ? gload(rc + offRow[2 * p])     : 0.0f;
          a2[p].y = okRow[2 * p + 1] ? gload(rc + offRow[2 * p + 1]) : 0.0f;
          b2[p].x = okRow[2 * p]     ? gload(rp + offRow[2 * p])     : 0.0f;
          b2[p].y = okRow[2 * p + 1] ? gload(rp + offRow[2 * p + 1]) : 0.0f;
        }
      }
      // no explicit waitcnt/barrier: compiler inserts per-value waits before
      // first use (halo ds_write); do_step's barrier orders cross-thread LDS.
    }

    float recv[KSTEPS];

    // one step, row-pair packed: p' = d2*c + c2*sum - prev (+ src)
    auto do_step = [&](v2f (&cur)[NPAIRS], v2f (&nxt)[NPAIRS], int tau) {
      const int pb = tau & 1;
      haloTop[pb][w][lane] = cur[0].x;
      haloBot[pb][w][lane] = cur[NPAIRS - 1].y;
      __syncthreads();
      if (tau > 0 && tid < nRec) recv[tau - 1] = recTile[1 - pb][myLz][myLx];
      const float up0 = (w > 0)          ? haloBot[pb][w - 1][lane] : 0.0f;
      const float dn7 = (w < NWAVES - 1) ? haloTop[pb][w + 1][lane] : 0.0f;
      const v2f av = { amp[tau], amp[tau] };
      #pragma unroll
      for (int p = 0; p < NPAIRS; ++p) {
        const float cx = cur[p].x, cy = cur[p].y;
        const float upx = (p == 0)          ? up0 : cur[p - 1].y;
        const float dny = (p == NPAIRS - 1) ? dn7 : cur[p + 1].x;
        v2f ud, lr;
        ud.x = upx + cy;                 // up(2p)+dn(2p)   (dn(2p)=cur[p].y)
        ud.y = cx + dny;                 // up(2p+1)+dn(2p+1) (up=cur[p].x)
        lr.x = nbr_left(cx) + nbr_right(cx);
        lr.y = nbr_left(cy) + nbr_right(cy);
        const v2f sum = ud + lr;                                   // pk_add
        v2f t = __builtin_elementwise_fma(c22[p], sum, -nxt[p]);   // pk_fma
        t = __builtin_elementwise_fma(d22[p], cur[p], t);          // pk_fma
        t = __builtin_elementwise_fma(srcM2[p], av, t);            // pk_fma
        nxt[p] = t;
      }
      if (recMask) {
        #pragma unroll
        for (int i = 0; i < RPT; ++i)
          if (recMask & (1u << i))
            recTile[pb][ilz + i][ilx] = (i & 1) ? nxt[i >> 1].y : nxt[i >> 1].x;
      }
    };

    #pragma unroll
    for (int h = 0; h < KSTEPS / 2; ++h) {
      do_step(a2, b2, 2 * h);
      do_step(b2, a2, 2 * h + 1);
    }

    if (ph != NPHASE - 1) {
      // interior writeback (LLC-coherent), then publish the phase flag.
      float* wc = (ph & 1) ? f1c : f0c;
      float* wp = (ph & 1) ? f1p : f0p;
      if (wbRow) {
        #pragma unroll
        for (int p = 0; p < NPAIRS; ++p) {
          gstore(wc + offRow[2 * p],     a2[p].x);
          gstore(wc + offRow[2 * p + 1], a2[p].y);
          gstore(wp + offRow[2 * p],     b2[p].x);
          gstore(wp + offRow[2 * p + 1], b2[p].y);
        }
      }
      __builtin_amdgcn_s_waitcnt(0);   // wb stores ack'd at LLC (per wave)
      __syncthreads();                 // whole WG drained + recTile[1] ready
      if (tid == 0) fstore(wF + (size_t)bid * LSTRIDE, (unsigned)(ph + 1));
    } else {
      __syncthreads();                 // recTile[1] ready
    }

    // receiver flush AFTER flag publication: out-store drain is off the
    // critical handshake path (normal cached stores; read after kernel end)
    if (tid < nRec) {
      recv[KSTEPS - 1] = recTile[1][myLz][myLx];
      #pragma unroll
      for (int t = 0; t < KSTEPS; ++t)
        out[(s * NT + (t0 + t)) * NRECS + myR] = recv[t];
    }
  }
}

extern "C" void kernel_launch(void* const* d_in, const int* in_sizes, int n_in,
                              void* d_out, int out_size, void* d_ws, size_t ws_size,
                              hipStream_t stream) {
  const float* x     = (const float*)d_in[0];
  const float* vp    = (const float*)d_in[1];
  const int*   src_z = (const int*)d_in[2];
  const int*   src_x = (const int*)d_in[3];
  const int*   rec_z = (const int*)d_in[4];
  const int*   rec_x = (const int*)d_in[5];
  float* out = (float*)d_out;

  float* ws = (float*)d_ws;
  const size_t F = (size_t)NSHOTS * NZ * NX;
  float* f0c = ws;
  float* f0p = ws + F;
  float* f1c = ws + 2 * F;
  float* f1p = ws + 3 * F;
  unsigned* bar = (unsigned*)(ws + 4 * F);

  // zero the wFlag region (128B-strided)
  hipMemsetAsync(bar, 0, (size_t)NWG * LSTRIDE * sizeof(unsigned), stream);

  wave_pk<<<dim3(NWG), dim3(BLOCK), 0, stream>>>(
      f0c, f0p, f1c, f1p, vp, x, src_z, src_x, rec_z, rec_x, out, bar);
}